// Round 9
// baseline (555.052 us; speedup 1.0000x reference)
//
#include <hip/hip_runtime.h>
#include <hip/hip_bf16.h>
#include <math.h>

#define N_TOTAL 32768
#define E_TOTAL 524288
#define NUM_GRAPHS 64
#define NPG 512
#define MAXD 64
#define KTOP 64
#define LATENT 513
#define PPAD 524

typedef __attribute__((ext_vector_type(8))) short bf16x8;
typedef __attribute__((ext_vector_type(4))) float f32x4;

__device__ __forceinline__ unsigned short f2bf(float f) {
    unsigned u = __float_as_uint(f);
    return (unsigned short)((u + 0x7FFFu + ((u >> 16) & 1u)) >> 16);   // RNE
}
__device__ __forceinline__ float bf2f(unsigned short h) {
    return __uint_as_float(((unsigned)h) << 16);
}
// XOR-swizzle within 128B granule keyed by row (applied at LDS write AND read)
__device__ __forceinline__ int swz(int bir, int row) {
    return (bir & ~127) | ((bir & 127) ^ ((row & 7) << 4));
}

// ---------------- setup ----------------

__global__ __launch_bounds__(256) void k_init(int* __restrict__ deg, int* __restrict__ cnt) {
    int i = blockIdx.x * 256 + threadIdx.x;
    if (i < N_TOTAL) { deg[i] = 1; cnt[i] = 0; }
}

__global__ __launch_bounds__(256) void k_zero(int4* __restrict__ p) {
    p[(size_t)blockIdx.x * 256 + threadIdx.x] = make_int4(0, 0, 0, 0);   // 4096 blocks = 16 MB
}

// adj/deg/cnt + byte-packed dense counts Au[g][v][u] (u8 each; max multiplicity << 256)
__global__ __launch_bounds__(256) void k_build(const int* __restrict__ ei,
                                               int* __restrict__ deg, int* __restrict__ cnt,
                                               int* __restrict__ adj, unsigned* __restrict__ Au) {
    int e = blockIdx.x * 256 + threadIdx.x;
    if (e >= E_TOTAL) return;
    int s = ei[e];
    int d = ei[E_TOTAL + e];
    atomicAdd(&deg[s], 1);
    int slot = atomicAdd(&cnt[d], 1);
    if (slot < MAXD) adj[(size_t)d * MAXD + slot] = s;
    int g = d >> 9, v = d & 511, u = s & 511;
    size_t bidx = ((size_t)(g * 512 + v) << 9) + u;        // byte index
    atomicAdd(&Au[bidx >> 2], 1u << ((u & 3) << 3));
}

// Au byte counts (+I) -> dense bf16 A' [g][v][u]
__global__ __launch_bounds__(256) void k_convA(const unsigned* __restrict__ Au,
                                               unsigned short* __restrict__ Asw) {
    size_t idx = (size_t)blockIdx.x * 256 + threadIdx.x;   // 2,097,152 threads (8 u each)
    int g = (int)(idx >> 15);
    int rem = (int)(idx & 32767);
    int v = rem >> 6;
    int u0 = (rem & 63) * 8;
    size_t ebase = ((size_t)(g * 512 + v) << 9) + u0;
    uint2 cw = *(const uint2*)(Au + (ebase >> 2));
    unsigned r[4];
#pragma unroll
    for (int i = 0; i < 4; ++i) {
        unsigned wv = (i < 2) ? cw.x : cw.y;
        int sh = (i & 1) * 16;
        int ua = u0 + 2 * i, ub = ua + 1;
        float ca = (float)((wv >> sh) & 0xFFu)       + ((ua == v) ? 1.f : 0.f);
        float cb = (float)((wv >> (sh + 8)) & 0xFFu) + ((ub == v) ? 1.f : 0.f);
        r[i] = (unsigned)f2bf(ca) | ((unsigned)f2bf(cb) << 16);
    }
    *(int4*)(Asw + ebase) = make_int4(r[0], r[1], r[2], r[3]);
}

// W prep: transpose + bf16 hi/lo split (proven)
__global__ __launch_bounds__(256) void k_prep(const float* __restrict__ Wc,
                                              unsigned short* __restrict__ Wth,
                                              unsigned short* __restrict__ Wtl) {
    __shared__ float tile[64][65];
    int b = blockIdx.x;
    int l = b >> 2, t = b & 3;
    int k0 = (t >> 1) * 64, o0 = (t & 1) * 64;
    int lane = threadIdx.x & 63, q = threadIdx.x >> 6;
    const float* Wsrc = Wc + (size_t)l * 16384;
#pragma unroll
    for (int it = 0; it < 16; ++it) {
        int r = it * 4 + q;
        tile[r][lane] = Wsrc[(size_t)(k0 + r) * 128 + o0 + lane];
    }
    __syncthreads();
#pragma unroll
    for (int it = 0; it < 16; ++it) {
        int o = it * 4 + q;
        float v = tile[lane][o];
        unsigned short h = f2bf(v);
        unsigned short lo = f2bf(v - bf2f(h));
        size_t dst = (size_t)l * 16384 + (size_t)(o0 + o) * 128 + k0 + lane;
        Wth[dst] = h; Wtl[dst] = lo;
    }
}

// layer-0 panels: emb[x[.]] -> transposed hi/lo panels [g][128ch][512u]  (proven)
__global__ __launch_bounds__(256) void k_embT(const int* __restrict__ x,
                                              const float* __restrict__ emb,
                                              unsigned short* __restrict__ Ph,
                                              unsigned short* __restrict__ Pl) {
    __shared__ float P[64][132];
    __shared__ int nodes[64];
    int b = blockIdx.x;               // 512 blocks: graph x 8 chunks of 64 nodes
    int g = b >> 3, ck = b & 7;
    int tid = threadIdx.x;
    if (tid < 64) nodes[tid] = x[g * NPG + ck * 64 + tid];
    __syncthreads();
#pragma unroll
    for (int c = 0; c < 8; ++c) {
        int idx = tid + c * 256;
        int row = idx >> 5, c4 = idx & 31;
        float4 vv = *(const float4*)(emb + (size_t)nodes[row] * 128 + c4 * 4);
        *(float4*)&P[row][c4 * 4] = vv;
    }
    __syncthreads();
#pragma unroll
    for (int c = 0; c < 4; ++c) {
        int idx = tid + c * 256;
        int ch = idx >> 3, grp = idx & 7;
        unsigned hw[4], lw[4];
#pragma unroll
        for (int j = 0; j < 4; ++j) {
            float a  = P[grp * 8 + 2 * j][ch];
            float bq = P[grp * 8 + 2 * j + 1][ch];
            unsigned short ha = f2bf(a),  hb = f2bf(bq);
            unsigned short la = f2bf(a - bf2f(ha)), lb = f2bf(bq - bf2f(hb));
            hw[j] = (unsigned)ha | ((unsigned)hb << 16);
            lw[j] = (unsigned)la | ((unsigned)lb << 16);
        }
        size_t base = ((size_t)g * 128 + ch) * 512 + ck * 64 + grp * 8;
        *(int4*)(Ph + base) = make_int4(hw[0], hw[1], hw[2], hw[3]);
        *(int4*)(Pl + base) = make_int4(lw[0], lw[1], lw[2], lw[3]);
    }
}

// ---------------- fused layer: dense MFMA, direct-global fragments, no staging ----------
// 512 blocks (graph x 8 v-blocks of 64). Phase1: S[64v][128ch] = A'[64][512] @ (Hh+Hl)^T
// with BOTH operands read straight from global ([row][k-contig] native layout).
// Phase2: Hout = tanh((S@W + (cnt+1)b)/deg) via LDS-bounced S (proven path).

__global__ __launch_bounds__(256) void k_layer(const unsigned short* __restrict__ Ph,
                                               const unsigned short* __restrict__ Pl,
                                               const unsigned short* __restrict__ Asw,
                                               const unsigned short* __restrict__ Wth,
                                               const unsigned short* __restrict__ Wtl,
                                               const float* __restrict__ bvec,
                                               const float* __restrict__ Wl,
                                               const float* __restrict__ bl,
                                               float* __restrict__ tmp,
                                               float* __restrict__ Hout,
                                               unsigned short* __restrict__ Poh,
                                               unsigned short* __restrict__ Pol,
                                               const int* __restrict__ cnt,
                                               const int* __restrict__ deg) {
    __shared__ char lds[32768];   // Sb_hi [0,16K), Sb_lo [16K,32K); reused as T_hi/T_lo
    int tid = threadIdx.x;
    int w = tid >> 6, lane = tid & 63;
    int bid = blockIdx.x;
    int g = (bid & 7) * 8 + ((bid >> 3) & 7);   // graph's 8 blocks share one XCD L2
    int vblk = bid >> 6;
    int nodebase = g * NPG + vblk * 64;
    int rowbase = nodebase + w * 16;
    int r = lane & 15, kb = lane >> 4;

    // ---- phase 1: no LDS, no barriers; frags straight from global/L2 ----
    f32x4 acc[8];
#pragma unroll
    for (int n = 0; n < 8; ++n) acc[n] = (f32x4){0.f, 0.f, 0.f, 0.f};
    const unsigned short* Arow = Asw + (size_t)(rowbase + r) * 512;    // A-op row v
    const unsigned short* Pbh  = Ph + ((size_t)g * 128 + r) * 512;     // B-op row ch (+n*16*512)
    const unsigned short* Pbl  = Pl + ((size_t)g * 128 + r) * 512;

    for (int kt = 0; kt < 8; ++kt) {
#pragma unroll
        for (int s2 = 0; s2 < 2; ++s2) {
            int ko = kt * 64 + s2 * 32 + kb * 8;
            bf16x8 aA = *(const bf16x8*)(Arow + ko);
#pragma unroll
            for (int n = 0; n < 8; ++n) {
                bf16x8 bh  = *(const bf16x8*)(Pbh + (size_t)n * 8192 + ko);
                bf16x8 bl2 = *(const bf16x8*)(Pbl + (size_t)n * 8192 + ko);
                acc[n] = __builtin_amdgcn_mfma_f32_16x16x32_bf16(aA, bh,  acc[n], 0, 0, 0);
                acc[n] = __builtin_amdgcn_mfma_f32_16x16x32_bf16(aA, bl2, acc[n], 0, 0, 0);
            }
        }
    }

    // ---- S -> Sb hi/lo in LDS (C-frag: v = w*16+kb*4+q, ch = n*16+r) ----
#pragma unroll
    for (int n = 0; n < 8; ++n) {
#pragma unroll
        for (int q = 0; q < 4; ++q) {
            int v64 = w * 16 + kb * 4 + q;
            int ch = n * 16 + r;
            float s = acc[n][q];
            unsigned short h = f2bf(s), lo = f2bf(s - bf2f(h));
            int addr = v64 * 256 + swz(ch * 2, v64);
            *(unsigned short*)(lds + addr)         = h;
            *(unsigned short*)(lds + 16384 + addr) = lo;
        }
    }
    __syncthreads();

    // ---- phase 2: Hout = tanh((S@W + (cnt+1)b)/deg) ----
    bf16x8 ah[4], al[4];
#pragma unroll
    for (int ks = 0; ks < 4; ++ks) {
        int v64 = w * 16 + r;
        int addr = v64 * 256 + swz(ks * 64 + kb * 16, v64);
        ah[ks] = *(const bf16x8*)(lds + addr);
        al[ks] = *(const bf16x8*)(lds + 16384 + addr);
    }
    float invd[4], cp1[4];
#pragma unroll
    for (int q = 0; q < 4; ++q) {
        int nd = rowbase + kb * 4 + q;
        invd[q] = 1.0f / (float)deg[nd];
        cp1[q]  = (float)(cnt[nd] + 1);
    }
    float z[4] = {0.f, 0.f, 0.f, 0.f};
    unsigned hiW[8][2], loW[8][2];
#pragma unroll
    for (int ct = 0; ct < 8; ++ct) {
        const unsigned short* Wh = Wth + (size_t)(ct * 16 + r) * 128;
        const unsigned short* Wo = Wtl + (size_t)(ct * 16 + r) * 128;
        f32x4 a = {0.f, 0.f, 0.f, 0.f};
#pragma unroll
        for (int ks = 0; ks < 4; ++ks) {
            bf16x8 wh = *(const bf16x8*)(Wh + ks * 32 + kb * 8);
            bf16x8 wl = *(const bf16x8*)(Wo + ks * 32 + kb * 8);
            a = __builtin_amdgcn_mfma_f32_16x16x32_bf16(ah[ks], wh, a, 0, 0, 0);
            a = __builtin_amdgcn_mfma_f32_16x16x32_bf16(ah[ks], wl, a, 0, 0, 0);
            a = __builtin_amdgcn_mfma_f32_16x16x32_bf16(al[ks], wh, a, 0, 0, 0);
        }
        float bcol = bvec[ct * 16 + r];
        float wlast = Wl ? Wl[ct * 16 + r] : 0.f;
        unsigned short hq[4], lq[4];
#pragma unroll
        for (int q = 0; q < 4; ++q) {
            float val = tanhf((a[q] + bcol * cp1[q]) * invd[q]);
            Hout[(size_t)(rowbase + kb * 4 + q) * 128 + ct * 16 + r] = val;
            z[q] = fmaf(val, wlast, z[q]);
            hq[q] = f2bf(val);
            lq[q] = f2bf(val - bf2f(hq[q]));
        }
        hiW[ct][0] = (unsigned)hq[0] | ((unsigned)hq[1] << 16);
        hiW[ct][1] = (unsigned)hq[2] | ((unsigned)hq[3] << 16);
        loW[ct][0] = (unsigned)lq[0] | ((unsigned)lq[1] << 16);
        loW[ct][1] = (unsigned)lq[2] | ((unsigned)lq[3] << 16);
    }

    // ---- next-layer panels via LDS-bounce transpose (T_hi@0, T_lo@16K) ----
    if (Poh) {
        __syncthreads();                         // all Sb reads done before overwrite
#pragma unroll
        for (int ct = 0; ct < 8; ++ct) {
            int o = ct * 16 + r;
            int v64 = w * 16 + kb * 4;
            int addr = o * 128 + swz(v64 * 2, o);
            *(int2*)(lds + addr)         = make_int2(hiW[ct][0], hiW[ct][1]);
            *(int2*)(lds + 16384 + addr) = make_int2(loW[ct][0], loW[ct][1]);
        }
        __syncthreads();
#pragma unroll
        for (int c = 0; c < 8; ++c) {
            int idx = tid + c * 256;             // 2048 16B units
            int arr = idx >> 10;
            int j = idx & 1023;
            int o = j >> 3, off16 = j & 7;
            int4 v = *(const int4*)(lds + arr * 16384 + o * 128 + swz(off16 * 16, o));
            unsigned short* dst = (arr ? Pol : Poh) + ((size_t)g * 128 + o) * 512 + vblk * 64 + off16 * 8;
            *(int4*)dst = v;
        }
    }

    // ---- fused last_lin (layer 3) ----
    if (Wl) {
#pragma unroll
        for (int m = 1; m < 16; m <<= 1) {
            z[0] += __shfl_xor(z[0], m); z[1] += __shfl_xor(z[1], m);
            z[2] += __shfl_xor(z[2], m); z[3] += __shfl_xor(z[3], m);
        }
        if (r == 0) {
            float b0 = bl[0];
#pragma unroll
            for (int q = 0; q < 4; ++q) tmp[rowbase + kb * 4 + q] = z[q] + b0;
        }
    }
}

// ---------------- sort pool (fused last-channel agg + exact bitonic) ----------------

__global__ __launch_bounds__(256) void k_sort(const float* __restrict__ tmp,
                                              const int* __restrict__ adj,
                                              const int* __restrict__ cnt,
                                              const int* __restrict__ deg,
                                              float* __restrict__ lastc,
                                              int* __restrict__ topk) {
    __shared__ float v[512];
    __shared__ int ix[512];
    int g = blockIdx.x, tid = threadIdx.x;
    for (int i = tid; i < 512; i += 256) {
        int node = g * NPG + i;
        float s = tmp[node];
        int c = cnt[node]; if (c > MAXD) c = MAXD;
        const int* av = adj + (size_t)node * MAXD;
#pragma unroll 4
        for (int q = 0; q < c; ++q) s += tmp[av[q]];
        float val = tanhf(s / (float)deg[node]);
        lastc[node] = val;
        v[i] = val; ix[i] = i;
    }
    __syncthreads();
    for (int ksz = 2; ksz <= 512; ksz <<= 1) {
        for (int jj = ksz >> 1; jj > 0; jj >>= 1) {
            for (int i = tid; i < 512; i += 256) {
                int p = i ^ jj;
                if (p > i) {
                    float va = v[i], vb = v[p];
                    int ia = ix[i], ib = ix[p];
                    bool b_before_a = (vb > va) || (vb == va && ib < ia);
                    bool up = (i & ksz) == 0;
                    bool sw = up ? b_before_a : !b_before_a;
                    if (sw) { v[i] = vb; v[p] = va; ix[i] = ib; ix[p] = ia; }
                }
            }
            __syncthreads();
        }
    }
    for (int k = tid; k < KTOP; k += 256) topk[g * KTOP + k] = g * NPG + ix[k];
}

// ---------------- conv1 + relu + maxpool ----------------

__global__ __launch_bounds__(256) void k_conv1(const int* __restrict__ topk,
                                               const float* __restrict__ h0,
                                               const float* __restrict__ h1,
                                               const float* __restrict__ h2,
                                               const float* __restrict__ h3,
                                               const float* __restrict__ lastc,
                                               const float* __restrict__ c1w,
                                               const float* __restrict__ c1b,
                                               float* __restrict__ y1p) {
    __shared__ float P[16][PPAD];
    __shared__ float Y1c[16][16];
    __shared__ int nodes[16];
    int bid = blockIdx.x;
    int g = bid >> 2, cc = bid & 3;
    int tid = threadIdx.x;
    if (tid < 16) nodes[tid] = topk[g * KTOP + cc * 16 + tid];
    __syncthreads();
    {
        int r = tid >> 4, t4 = tid & 15;
        int node = nodes[r];
#pragma unroll
        for (int jj = 0; jj < 8; ++jj) {
            int d = (t4 + 16 * jj) * 4;
            const float* src = (d < 128) ? h0 : (d < 256) ? h1 : (d < 384) ? h2 : h3;
            float4 val = *(const float4*)(src + (size_t)node * 128 + (d & 127));
            *(float4*)&P[r][d] = val;
        }
        if (t4 == 0) P[r][512] = lastc[node];
    }
    __syncthreads();
    int o = tid >> 4, kk = tid & 15;
    const float* w = c1w + (size_t)o * LATENT;
    float a0 = 0.f, a1 = 0.f, a2 = 0.f, a3 = 0.f;
    for (int d = 0; d < 512; d += 4) {
        float4 p = *(const float4*)&P[kk][d];
        a0 = fmaf(p.x, w[d],     a0);
        a1 = fmaf(p.y, w[d + 1], a1);
        a2 = fmaf(p.z, w[d + 2], a2);
        a3 = fmaf(p.w, w[d + 3], a3);
    }
    float s = ((a0 + a1) + (a2 + a3)) + P[kk][512] * w[512] + c1b[o];
    Y1c[o][kk] = fmaxf(s, 0.f);
    __syncthreads();
    if (tid < 128) {
        int oo = tid >> 3, l = tid & 7;
        y1p[(size_t)g * 512 + oo * 32 + cc * 8 + l] = fmaxf(Y1c[oo][2 * l], Y1c[oo][2 * l + 1]);
    }
}

// ---------------- conv2 + dense + softmax ----------------

__global__ __launch_bounds__(256) void k_tail(const float* __restrict__ y1p,
                                              const float* __restrict__ c2w, const float* __restrict__ c2b,
                                              const float* __restrict__ d1w, const float* __restrict__ d1b,
                                              const float* __restrict__ d2w, const float* __restrict__ d2b,
                                              float* __restrict__ out) {
    __shared__ float Y1P[16][32];
    __shared__ float Y2[32][28];
    __shared__ float H1s[32];
    __shared__ float red[256];
    int g = blockIdx.x, tid = threadIdx.x;
    for (int t = tid; t < 512; t += 256) ((float*)Y1P)[t] = y1p[(size_t)g * 512 + t];
    __syncthreads();
    for (int t = tid; t < 32 * 28; t += 256) {
        int o2 = t / 28, tt = t - o2 * 28;
        float s = c2b[o2];
#pragma unroll
        for (int i = 0; i < 16; ++i)
#pragma unroll
            for (int dt = 0; dt < 5; ++dt)
                s = fmaf(Y1P[i][tt + dt], c2w[o2 * 80 + i * 5 + dt], s);
        Y2[o2][tt] = fmaxf(s, 0.f);
    }
    __syncthreads();
    {
        int jcol = tid >> 3, part = tid & 7;
        float s = 0.f;
        for (int rr = 0; rr < 4; ++rr) {
            int o2 = part * 4 + rr;
            int base = o2 * 28;
            for (int tt = 0; tt < 28; ++tt)
                s = fmaf(Y2[o2][tt], d1w[(size_t)(base + tt) * 32 + jcol], s);
        }
        red[tid] = s;
        __syncthreads();
        if (part == 0) {
            float t = 0.f;
#pragma unroll
            for (int p = 0; p < 8; ++p) t += red[tid + p];
            H1s[jcol] = fmaxf(t + d1b[jcol], 0.f);
        }
        __syncthreads();
    }
    if (tid == 0) {
        float l0 = d2b[0], l1 = d2b[1];
        for (int jc = 0; jc < 32; ++jc) {
            l0 = fmaf(H1s[jc], d2w[jc * 2 + 0], l0);
            l1 = fmaf(H1s[jc], d2w[jc * 2 + 1], l1);
        }
        float m = fmaxf(l0, l1);
        float e0 = expf(l0 - m), e1 = expf(l1 - m);
        float inv = 1.f / (e0 + e1);
        out[g * 2 + 0] = e0 * inv;
        out[g * 2 + 1] = e1 * inv;
    }
}

// ---------------- launch ----------------

extern "C" void kernel_launch(void* const* d_in, const int* in_sizes, int n_in,
                              void* d_out, int out_size, void* d_ws, size_t ws_size,
                              hipStream_t stream) {
    const int*   x    = (const int*)d_in[0];
    const int*   ei   = (const int*)d_in[1];
    const float* emb  = (const float*)d_in[3];
    const float* Wc   = (const float*)d_in[4];
    const float* bc   = (const float*)d_in[5];
    const float* Wl   = (const float*)d_in[6];
    const float* bl   = (const float*)d_in[7];
    const float* c1w  = (const float*)d_in[8];
    const float* c1b  = (const float*)d_in[9];
    const float* c2w  = (const float*)d_in[10];
    const float* c2b  = (const float*)d_in[11];
    const float* d1w  = (const float*)d_in[12];
    const float* d1b  = (const float*)d_in[13];
    const float* d2w  = (const float*)d_in[14];
    const float* d2b  = (const float*)d_in[15];
    float* out = (float*)d_out;

    char* ws = (char*)d_ws;
    int*   deg  = (int*)ws;            ws += (size_t)N_TOTAL * 4;
    int*   cnt  = (int*)ws;            ws += (size_t)N_TOTAL * 4;
    int*   adj  = (int*)ws;            ws += (size_t)N_TOTAL * MAXD * 4;
    float* Hid0 = (float*)ws;          ws += (size_t)N_TOTAL * 128 * 4;
    float* Hid1 = (float*)ws;          ws += (size_t)N_TOTAL * 128 * 4;
    float* Hid2 = (float*)ws;          ws += (size_t)N_TOTAL * 128 * 4;
    float* Hid3 = (float*)ws;          ws += (size_t)N_TOTAL * 128 * 4;
    unsigned short* Wth = (unsigned short*)ws;  ws += (size_t)4 * 128 * 128 * 2;
    unsigned short* Wtl = (unsigned short*)ws;  ws += (size_t)4 * 128 * 128 * 2;
    float* tmp  = (float*)ws;          ws += (size_t)N_TOTAL * 4;
    float* lastc= (float*)ws;          ws += (size_t)N_TOTAL * 4;
    int*   topk = (int*)ws;            ws += (size_t)NUM_GRAPHS * KTOP * 4;
    float* y1p  = (float*)ws;          ws += (size_t)NUM_GRAPHS * 16 * 32 * 4;
    unsigned* Au = (unsigned*)ws;      ws += (size_t)NUM_GRAPHS * 512 * 512;       // 16 MB (u8)
    unsigned short* Asw = (unsigned short*)ws;  ws += (size_t)NUM_GRAPHS * 512 * 512 * 2; // 32 MB
    unsigned short* PAh = (unsigned short*)ws;  ws += (size_t)NUM_GRAPHS * 128 * 512 * 2;
    unsigned short* PAl = (unsigned short*)ws;  ws += (size_t)NUM_GRAPHS * 128 * 512 * 2;
    unsigned short* PBh = (unsigned short*)ws;  ws += (size_t)NUM_GRAPHS * 128 * 512 * 2;
    unsigned short* PBl = (unsigned short*)ws;  ws += (size_t)NUM_GRAPHS * 128 * 512 * 2;

    k_init <<<N_TOTAL / 256, 256, 0, stream>>>(deg, cnt);
    k_zero <<<4096, 256, 0, stream>>>((int4*)Au);
    k_build<<<E_TOTAL / 256, 256, 0, stream>>>(ei, deg, cnt, adj, Au);
    k_prep <<<16, 256, 0, stream>>>(Wc, Wth, Wtl);
    k_convA<<<8192, 256, 0, stream>>>(Au, Asw);
    k_embT <<<NUM_GRAPHS * 8, 256, 0, stream>>>(x, emb, PAh, PAl);

    float* Hids[4] = {Hid0, Hid1, Hid2, Hid3};
    unsigned short* Pin_h[4] = {PAh, PBh, PAh, PBh};
    unsigned short* Pin_l[4] = {PAl, PBl, PAl, PBl};
    unsigned short* Pout_h[4] = {PBh, PAh, PBh, nullptr};
    unsigned short* Pout_l[4] = {PBl, PAl, PBl, nullptr};
    for (int l = 0; l < 4; ++l) {
        const float* wl  = (l == 3) ? Wl : nullptr;
        const float* blp = (l == 3) ? bl : nullptr;
        float*       tp  = (l == 3) ? tmp : nullptr;
        k_layer<<<512, 256, 0, stream>>>(Pin_h[l], Pin_l[l], Asw,
                                         Wth + (size_t)l * 16384, Wtl + (size_t)l * 16384,
                                         bc + (size_t)l * 128, wl, blp, tp,
                                         Hids[l], Pout_h[l], Pout_l[l], cnt, deg);
    }
    k_sort <<<NUM_GRAPHS, 256, 0, stream>>>(tmp, adj, cnt, deg, lastc, topk);
    k_conv1<<<NUM_GRAPHS * 4, 256, 0, stream>>>(topk, Hid0, Hid1, Hid2, Hid3, lastc, c1w, c1b, y1p);
    k_tail <<<NUM_GRAPHS, 256, 0, stream>>>(y1p, c2w, c2b, d1w, d1b, d2w, d2b, out);
}

// Round 10
// 332.614 us; speedup vs baseline: 1.6688x; 1.6688x over previous
//
#include <hip/hip_runtime.h>
#include <hip/hip_bf16.h>
#include <math.h>

#define N_TOTAL 32768
#define E_TOTAL 524288
#define NUM_GRAPHS 64
#define NPG 512
#define MAXD 64
#define KTOP 64
#define LATENT 513
#define PPAD 524

typedef __attribute__((ext_vector_type(8))) short bf16x8;
typedef __attribute__((ext_vector_type(4))) float f32x4;

__device__ __forceinline__ unsigned short f2bf(float f) {
    unsigned u = __float_as_uint(f);
    return (unsigned short)((u + 0x7FFFu + ((u >> 16) & 1u)) >> 16);   // RNE
}
__device__ __forceinline__ float bf2f(unsigned short h) {
    return __uint_as_float(((unsigned)h) << 16);
}
// XOR-swizzle within 128B granule keyed by row (write AND read sides)
__device__ __forceinline__ int swz(int bir, int row) {
    return (bir & ~127) | ((bir & 127) ^ ((row & 7) << 4));
}

// ---------------- setup ----------------

__global__ __launch_bounds__(256) void k_init(int* __restrict__ deg, int* __restrict__ cnt) {
    int i = blockIdx.x * 256 + threadIdx.x;
    if (i < N_TOTAL) { deg[i] = 1; cnt[i] = 0; }
}

__global__ __launch_bounds__(256) void k_zero(int4* __restrict__ p) {
    p[(size_t)blockIdx.x * 256 + threadIdx.x] = make_int4(0, 0, 0, 0);   // 4096 blocks = 16 MB
}

// adj/deg/cnt + byte-packed dense counts Au[g][v][u]
__global__ __launch_bounds__(256) void k_build(const int* __restrict__ ei,
                                               int* __restrict__ deg, int* __restrict__ cnt,
                                               int* __restrict__ adj, unsigned* __restrict__ Au) {
    int e = blockIdx.x * 256 + threadIdx.x;
    if (e >= E_TOTAL) return;
    int s = ei[e];
    int d = ei[E_TOTAL + e];
    atomicAdd(&deg[s], 1);
    int slot = atomicAdd(&cnt[d], 1);
    if (slot < MAXD) adj[(size_t)d * MAXD + slot] = s;
    int g = d >> 9, v = d & 511, u = s & 511;
    size_t bidx = ((size_t)(g * 512 + v) << 9) + u;
    atomicAdd(&Au[bidx >> 2], 1u << ((u & 3) << 3));
}

// Au byte counts (+I) -> dense bf16 A' [g][v][u]
__global__ __launch_bounds__(256) void k_convA(const unsigned* __restrict__ Au,
                                               unsigned short* __restrict__ Asw) {
    size_t idx = (size_t)blockIdx.x * 256 + threadIdx.x;
    int g = (int)(idx >> 15);
    int rem = (int)(idx & 32767);
    int v = rem >> 6;
    int u0 = (rem & 63) * 8;
    size_t ebase = ((size_t)(g * 512 + v) << 9) + u0;
    uint2 cw = *(const uint2*)(Au + (ebase >> 2));
    unsigned r[4];
#pragma unroll
    for (int i = 0; i < 4; ++i) {
        unsigned wv = (i < 2) ? cw.x : cw.y;
        int sh = (i & 1) * 16;
        int ua = u0 + 2 * i, ub = ua + 1;
        float ca = (float)((wv >> sh) & 0xFFu)       + ((ua == v) ? 1.f : 0.f);
        float cb = (float)((wv >> (sh + 8)) & 0xFFu) + ((ub == v) ? 1.f : 0.f);
        r[i] = (unsigned)f2bf(ca) | ((unsigned)f2bf(cb) << 16);
    }
    *(int4*)(Asw + ebase) = make_int4(r[0], r[1], r[2], r[3]);
}

// W prep: transpose + bf16 hi/lo split (proven)
__global__ __launch_bounds__(256) void k_prep(const float* __restrict__ Wc,
                                              unsigned short* __restrict__ Wth,
                                              unsigned short* __restrict__ Wtl) {
    __shared__ float tile[64][65];
    int b = blockIdx.x;
    int l = b >> 2, t = b & 3;
    int k0 = (t >> 1) * 64, o0 = (t & 1) * 64;
    int lane = threadIdx.x & 63, q = threadIdx.x >> 6;
    const float* Wsrc = Wc + (size_t)l * 16384;
#pragma unroll
    for (int it = 0; it < 16; ++it) {
        int r = it * 4 + q;
        tile[r][lane] = Wsrc[(size_t)(k0 + r) * 128 + o0 + lane];
    }
    __syncthreads();
#pragma unroll
    for (int it = 0; it < 16; ++it) {
        int o = it * 4 + q;
        float v = tile[lane][o];
        unsigned short h = f2bf(v);
        unsigned short lo = f2bf(v - bf2f(h));
        size_t dst = (size_t)l * 16384 + (size_t)(o0 + o) * 128 + k0 + lane;
        Wth[dst] = h; Wtl[dst] = lo;
    }
}

// layer-0 panels: emb[x[.]] -> transposed hi/lo panels [g][128ch][512u]  (proven)
__global__ __launch_bounds__(256) void k_embT(const int* __restrict__ x,
                                              const float* __restrict__ emb,
                                              unsigned short* __restrict__ Ph,
                                              unsigned short* __restrict__ Pl) {
    __shared__ float P[64][132];
    __shared__ int nodes[64];
    int b = blockIdx.x;
    int g = b >> 3, ck = b & 7;
    int tid = threadIdx.x;
    if (tid < 64) nodes[tid] = x[g * NPG + ck * 64 + tid];
    __syncthreads();
#pragma unroll
    for (int c = 0; c < 8; ++c) {
        int idx = tid + c * 256;
        int row = idx >> 5, c4 = idx & 31;
        float4 vv = *(const float4*)(emb + (size_t)nodes[row] * 128 + c4 * 4);
        *(float4*)&P[row][c4 * 4] = vv;
    }
    __syncthreads();
#pragma unroll
    for (int c = 0; c < 4; ++c) {
        int idx = tid + c * 256;
        int ch = idx >> 3, grp = idx & 7;
        unsigned hw[4], lw[4];
#pragma unroll
        for (int j = 0; j < 4; ++j) {
            float a  = P[grp * 8 + 2 * j][ch];
            float bq = P[grp * 8 + 2 * j + 1][ch];
            unsigned short ha = f2bf(a),  hb = f2bf(bq);
            unsigned short la = f2bf(a - bf2f(ha)), lb = f2bf(bq - bf2f(hb));
            hw[j] = (unsigned)ha | ((unsigned)hb << 16);
            lw[j] = (unsigned)la | ((unsigned)lb << 16);
        }
        size_t base = ((size_t)g * 128 + ch) * 512 + ck * 64 + grp * 8;
        *(int4*)(Ph + base) = make_int4(hw[0], hw[1], hw[2], hw[3]);
        *(int4*)(Pl + base) = make_int4(lw[0], lw[1], lw[2], lw[3]);
    }
}

// ---------------- fused layer: dense MFMA; B in LDS (async dbuf), A direct-global --------
// 512 blocks (graph x 8 v-blocks of 64). Per K-tile (BK=64): stage Bh+Bl (32 KB) via
// global_load_lds into the OTHER buffer, compute current from LDS, ONE barrier per tile.
// LDS dest linear (HW requirement); swizzle carried by pre-swizzled GLOBAL source (m173).

__global__ __launch_bounds__(256) void k_layer(const unsigned short* __restrict__ Ph,
                                               const unsigned short* __restrict__ Pl,
                                               const unsigned short* __restrict__ Asw,
                                               const unsigned short* __restrict__ Wth,
                                               const unsigned short* __restrict__ Wtl,
                                               const float* __restrict__ bvec,
                                               const float* __restrict__ Wl,
                                               const float* __restrict__ bl,
                                               float* __restrict__ tmp,
                                               float* __restrict__ Hout,
                                               unsigned short* __restrict__ Poh,
                                               unsigned short* __restrict__ Pol,
                                               const int* __restrict__ cnt,
                                               const int* __restrict__ deg) {
    __shared__ char lds[65536];   // two 32KB B-buffers; [0,32K) reused for Sb / panel bounce
    int tid = threadIdx.x;
    int w = tid >> 6, lane = tid & 63;
    int bid = blockIdx.x;
    int g = (bid & 7) * 8 + ((bid >> 3) & 7);   // graph's 8 blocks share one XCD L2
    int vblk = bid >> 6;
    int nodebase = g * NPG + vblk * 64;
    int rowbase = nodebase + w * 16;
    int r = lane & 15, kb = lane >> 4;

    const unsigned short* Pgh = Ph + (size_t)g * 128 * 512;
    const unsigned short* Pgl = Pl + (size_t)g * 128 * 512;
    const unsigned short* Arow = Asw + (size_t)(rowbase + r) * 512;

    // stage one 64-k B tile (Bh 16KB + Bl 16KB) into buffer `buf`
    // slot s in [0,2048): arr=s>>10 (0=hi,1=lo), row=(s&1023)>>3, off16=s&7
    // LDS linear [arr][row][off16]; global src element index off16^(row&7)  -> swizzled reads
#define STAGE(buf, kt)                                                                     \
    {                                                                                      \
        _Pragma("unroll")                                                                  \
        for (int c = 0; c < 8; ++c) {                                                      \
            int sb = c * 256 + w * 64;            /* wave-uniform slot base */             \
            int slot = sb + lane;                                                          \
            int arr = slot >> 10;                                                          \
            int j = slot & 1023;                                                           \
            int row = j >> 3, off16 = j & 7;                                               \
            const unsigned short* src = (arr ? Pgl : Pgh)                                  \
                + (size_t)row * 512 + (kt) * 64 + ((off16 ^ (row & 7)) << 3);              \
            char* dst = lds + (buf) * 32768 + sb * 16;   /* wave-uniform; HW adds lane*16*/\
            __builtin_amdgcn_global_load_lds((const unsigned*)src, (unsigned*)dst,         \
                                             16, 0, 0);                                    \
        }                                                                                  \
    }

    // ---- phase 1: S[64v][128ch] = A' @ (Bh + Bl), 8 K-tiles, 2-phase pipeline ----
    f32x4 acc[8];
#pragma unroll
    for (int n = 0; n < 8; ++n) acc[n] = (f32x4){0.f, 0.f, 0.f, 0.f};

    STAGE(0, 0);
    __syncthreads();
    int cbuf = 0;
    for (int kt = 0; kt < 8; ++kt) {
        if (kt < 7) STAGE(cbuf ^ 1, kt + 1);     // prefetch next tile (async)
        const char* cur = lds + cbuf * 32768;
#pragma unroll
        for (int s2 = 0; s2 < 2; ++s2) {
            bf16x8 aA = *(const bf16x8*)(Arow + kt * 64 + s2 * 32 + kb * 8);
#pragma unroll
            for (int n = 0; n < 8; ++n) {
                int ch = n * 16 + r;
                int u = s2 * 4 + kb;
                int boff = ch * 128 + ((u ^ (ch & 7)) << 4);
                bf16x8 bh  = *(const bf16x8*)(cur + boff);
                bf16x8 bl2 = *(const bf16x8*)(cur + 16384 + boff);
                acc[n] = __builtin_amdgcn_mfma_f32_16x16x32_bf16(aA, bh,  acc[n], 0, 0, 0);
                acc[n] = __builtin_amdgcn_mfma_f32_16x16x32_bf16(aA, bl2, acc[n], 0, 0, 0);
            }
        }
        __syncthreads();                          // drains prefetch too (had full tile to fly)
        cbuf ^= 1;
    }
#undef STAGE

    // ---- S -> Sb hi/lo in LDS (C-frag: v = w*16+kb*4+q, ch = n*16+r) ----
#pragma unroll
    for (int n = 0; n < 8; ++n) {
#pragma unroll
        for (int q = 0; q < 4; ++q) {
            int v64 = w * 16 + kb * 4 + q;
            int ch = n * 16 + r;
            float s = acc[n][q];
            unsigned short h = f2bf(s), lo = f2bf(s - bf2f(h));
            int addr = v64 * 256 + swz(ch * 2, v64);
            *(unsigned short*)(lds + addr)         = h;
            *(unsigned short*)(lds + 16384 + addr) = lo;
        }
    }
    __syncthreads();

    // ---- phase 2: Hout = tanh((S@W + (cnt+1)b)/deg) ----
    bf16x8 ah[4], al[4];
#pragma unroll
    for (int ks = 0; ks < 4; ++ks) {
        int v64 = w * 16 + r;
        int addr = v64 * 256 + swz(ks * 64 + kb * 16, v64);
        ah[ks] = *(const bf16x8*)(lds + addr);
        al[ks] = *(const bf16x8*)(lds + 16384 + addr);
    }
    float invd[4], cp1[4];
#pragma unroll
    for (int q = 0; q < 4; ++q) {
        int nd = rowbase + kb * 4 + q;
        invd[q] = 1.0f / (float)deg[nd];
        cp1[q]  = (float)(cnt[nd] + 1);
    }
    float z[4] = {0.f, 0.f, 0.f, 0.f};
    unsigned hiW[8][2], loW[8][2];
#pragma unroll
    for (int ct = 0; ct < 8; ++ct) {
        const unsigned short* Wh = Wth + (size_t)(ct * 16 + r) * 128;
        const unsigned short* Wo = Wtl + (size_t)(ct * 16 + r) * 128;
        f32x4 a = {0.f, 0.f, 0.f, 0.f};
#pragma unroll
        for (int ks = 0; ks < 4; ++ks) {
            bf16x8 wh = *(const bf16x8*)(Wh + ks * 32 + kb * 8);
            bf16x8 wl = *(const bf16x8*)(Wo + ks * 32 + kb * 8);
            a = __builtin_amdgcn_mfma_f32_16x16x32_bf16(ah[ks], wh, a, 0, 0, 0);
            a = __builtin_amdgcn_mfma_f32_16x16x32_bf16(ah[ks], wl, a, 0, 0, 0);
            a = __builtin_amdgcn_mfma_f32_16x16x32_bf16(al[ks], wh, a, 0, 0, 0);
        }
        float bcol = bvec[ct * 16 + r];
        float wlast = Wl ? Wl[ct * 16 + r] : 0.f;
        unsigned short hq[4], lq[4];
#pragma unroll
        for (int q = 0; q < 4; ++q) {
            float val = tanhf((a[q] + bcol * cp1[q]) * invd[q]);
            Hout[(size_t)(rowbase + kb * 4 + q) * 128 + ct * 16 + r] = val;
            z[q] = fmaf(val, wlast, z[q]);
            hq[q] = f2bf(val);
            lq[q] = f2bf(val - bf2f(hq[q]));
        }
        hiW[ct][0] = (unsigned)hq[0] | ((unsigned)hq[1] << 16);
        hiW[ct][1] = (unsigned)hq[2] | ((unsigned)hq[3] << 16);
        loW[ct][0] = (unsigned)lq[0] | ((unsigned)lq[1] << 16);
        loW[ct][1] = (unsigned)lq[2] | ((unsigned)lq[3] << 16);
    }

    // ---- next-layer panels via LDS-bounce transpose (T_hi@0, T_lo@16K) ----
    if (Poh) {
        __syncthreads();
#pragma unroll
        for (int ct = 0; ct < 8; ++ct) {
            int o = ct * 16 + r;
            int v64 = w * 16 + kb * 4;
            int addr = o * 128 + swz(v64 * 2, o);
            *(int2*)(lds + addr)         = make_int2(hiW[ct][0], hiW[ct][1]);
            *(int2*)(lds + 16384 + addr) = make_int2(loW[ct][0], loW[ct][1]);
        }
        __syncthreads();
#pragma unroll
        for (int c = 0; c < 8; ++c) {
            int idx = tid + c * 256;
            int arr = idx >> 10;
            int j = idx & 1023;
            int o = j >> 3, off16 = j & 7;
            int4 v = *(const int4*)(lds + arr * 16384 + o * 128 + swz(off16 * 16, o));
            unsigned short* dst = (arr ? Pol : Poh) + ((size_t)g * 128 + o) * 512 + vblk * 64 + off16 * 8;
            *(int4*)dst = v;
        }
    }

    // ---- fused last_lin (layer 3) ----
    if (Wl) {
#pragma unroll
        for (int m = 1; m < 16; m <<= 1) {
            z[0] += __shfl_xor(z[0], m); z[1] += __shfl_xor(z[1], m);
            z[2] += __shfl_xor(z[2], m); z[3] += __shfl_xor(z[3], m);
        }
        if (r == 0) {
            float b0 = bl[0];
#pragma unroll
            for (int q = 0; q < 4; ++q) tmp[rowbase + kb * 4 + q] = z[q] + b0;
        }
    }
}

// ---------------- sort pool (fused last-channel agg + exact bitonic) ----------------

__global__ __launch_bounds__(256) void k_sort(const float* __restrict__ tmp,
                                              const int* __restrict__ adj,
                                              const int* __restrict__ cnt,
                                              const int* __restrict__ deg,
                                              float* __restrict__ lastc,
                                              int* __restrict__ topk) {
    __shared__ float v[512];
    __shared__ int ix[512];
    int g = blockIdx.x, tid = threadIdx.x;
    for (int i = tid; i < 512; i += 256) {
        int node = g * NPG + i;
        float s = tmp[node];
        int c = cnt[node]; if (c > MAXD) c = MAXD;
        const int* av = adj + (size_t)node * MAXD;
#pragma unroll 4
        for (int q = 0; q < c; ++q) s += tmp[av[q]];
        float val = tanhf(s / (float)deg[node]);
        lastc[node] = val;
        v[i] = val; ix[i] = i;
    }
    __syncthreads();
    for (int ksz = 2; ksz <= 512; ksz <<= 1) {
        for (int jj = ksz >> 1; jj > 0; jj >>= 1) {
            for (int i = tid; i < 512; i += 256) {
                int p = i ^ jj;
                if (p > i) {
                    float va = v[i], vb = v[p];
                    int ia = ix[i], ib = ix[p];
                    bool b_before_a = (vb > va) || (vb == va && ib < ia);
                    bool up = (i & ksz) == 0;
                    bool sw = up ? b_before_a : !b_before_a;
                    if (sw) { v[i] = vb; v[p] = va; ix[i] = ib; ix[p] = ia; }
                }
            }
            __syncthreads();
        }
    }
    for (int k = tid; k < KTOP; k += 256) topk[g * KTOP + k] = g * NPG + ix[k];
}

// ---------------- conv1 + relu + maxpool ----------------

__global__ __launch_bounds__(256) void k_conv1(const int* __restrict__ topk,
                                               const float* __restrict__ h0,
                                               const float* __restrict__ h1,
                                               const float* __restrict__ h2,
                                               const float* __restrict__ h3,
                                               const float* __restrict__ lastc,
                                               const float* __restrict__ c1w,
                                               const float* __restrict__ c1b,
                                               float* __restrict__ y1p) {
    __shared__ float P[16][PPAD];
    __shared__ float Y1c[16][16];
    __shared__ int nodes[16];
    int bid = blockIdx.x;
    int g = bid >> 2, cc = bid & 3;
    int tid = threadIdx.x;
    if (tid < 16) nodes[tid] = topk[g * KTOP + cc * 16 + tid];
    __syncthreads();
    {
        int r = tid >> 4, t4 = tid & 15;
        int node = nodes[r];
#pragma unroll
        for (int jj = 0; jj < 8; ++jj) {
            int d = (t4 + 16 * jj) * 4;
            const float* src = (d < 128) ? h0 : (d < 256) ? h1 : (d < 384) ? h2 : h3;
            float4 val = *(const float4*)(src + (size_t)node * 128 + (d & 127));
            *(float4*)&P[r][d] = val;
        }
        if (t4 == 0) P[r][512] = lastc[node];
    }
    __syncthreads();
    int o = tid >> 4, kk = tid & 15;
    const float* w = c1w + (size_t)o * LATENT;
    float a0 = 0.f, a1 = 0.f, a2 = 0.f, a3 = 0.f;
    for (int d = 0; d < 512; d += 4) {
        float4 p = *(const float4*)&P[kk][d];
        a0 = fmaf(p.x, w[d],     a0);
        a1 = fmaf(p.y, w[d + 1], a1);
        a2 = fmaf(p.z, w[d + 2], a2);
        a3 = fmaf(p.w, w[d + 3], a3);
    }
    float s = ((a0 + a1) + (a2 + a3)) + P[kk][512] * w[512] + c1b[o];
    Y1c[o][kk] = fmaxf(s, 0.f);
    __syncthreads();
    if (tid < 128) {
        int oo = tid >> 3, l = tid & 7;
        y1p[(size_t)g * 512 + oo * 32 + cc * 8 + l] = fmaxf(Y1c[oo][2 * l], Y1c[oo][2 * l + 1]);
    }
}

// ---------------- conv2 + dense + softmax ----------------

__global__ __launch_bounds__(256) void k_tail(const float* __restrict__ y1p,
                                              const float* __restrict__ c2w, const float* __restrict__ c2b,
                                              const float* __restrict__ d1w, const float* __restrict__ d1b,
                                              const float* __restrict__ d2w, const float* __restrict__ d2b,
                                              float* __restrict__ out) {
    __shared__ float Y1P[16][32];
    __shared__ float Y2[32][28];
    __shared__ float H1s[32];
    __shared__ float red[256];
    int g = blockIdx.x, tid = threadIdx.x;
    for (int t = tid; t < 512; t += 256) ((float*)Y1P)[t] = y1p[(size_t)g * 512 + t];
    __syncthreads();
    for (int t = tid; t < 32 * 28; t += 256) {
        int o2 = t / 28, tt = t - o2 * 28;
        float s = c2b[o2];
#pragma unroll
        for (int i = 0; i < 16; ++i)
#pragma unroll
            for (int dt = 0; dt < 5; ++dt)
                s = fmaf(Y1P[i][tt + dt], c2w[o2 * 80 + i * 5 + dt], s);
        Y2[o2][tt] = fmaxf(s, 0.f);
    }
    __syncthreads();
    {
        int jcol = tid >> 3, part = tid & 7;
        float s = 0.f;
        for (int rr = 0; rr < 4; ++rr) {
            int o2 = part * 4 + rr;
            int base = o2 * 28;
            for (int tt = 0; tt < 28; ++tt)
                s = fmaf(Y2[o2][tt], d1w[(size_t)(base + tt) * 32 + jcol], s);
        }
        red[tid] = s;
        __syncthreads();
        if (part == 0) {
            float t = 0.f;
#pragma unroll
            for (int p = 0; p < 8; ++p) t += red[tid + p];
            H1s[jcol] = fmaxf(t + d1b[jcol], 0.f);
        }
        __syncthreads();
    }
    if (tid == 0) {
        float l0 = d2b[0], l1 = d2b[1];
        for (int jc = 0; jc < 32; ++jc) {
            l0 = fmaf(H1s[jc], d2w[jc * 2 + 0], l0);
            l1 = fmaf(H1s[jc], d2w[jc * 2 + 1], l1);
        }
        float m = fmaxf(l0, l1);
        float e0 = expf(l0 - m), e1 = expf(l1 - m);
        float inv = 1.f / (e0 + e1);
        out[g * 2 + 0] = e0 * inv;
        out[g * 2 + 1] = e1 * inv;
    }
}

// ---------------- launch ----------------

extern "C" void kernel_launch(void* const* d_in, const int* in_sizes, int n_in,
                              void* d_out, int out_size, void* d_ws, size_t ws_size,
                              hipStream_t stream) {
    const int*   x    = (const int*)d_in[0];
    const int*   ei   = (const int*)d_in[1];
    const float* emb  = (const float*)d_in[3];
    const float* Wc   = (const float*)d_in[4];
    const float* bc   = (const float*)d_in[5];
    const float* Wl   = (const float*)d_in[6];
    const float* bl   = (const float*)d_in[7];
    const float* c1w  = (const float*)d_in[8];
    const float* c1b  = (const float*)d_in[9];
    const float* c2w  = (const float*)d_in[10];
    const float* c2b  = (const float*)d_in[11];
    const float* d1w  = (const float*)d_in[12];
    const float* d1b  = (const float*)d_in[13];
    const float* d2w  = (const float*)d_in[14];
    const float* d2b  = (const float*)d_in[15];
    float* out = (float*)d_out;

    char* ws = (char*)d_ws;
    int*   deg  = (int*)ws;            ws += (size_t)N_TOTAL * 4;
    int*   cnt  = (int*)ws;            ws += (size_t)N_TOTAL * 4;
    int*   adj  = (int*)ws;            ws += (size_t)N_TOTAL * MAXD * 4;
    float* Hid0 = (float*)ws;          ws += (size_t)N_TOTAL * 128 * 4;
    float* Hid1 = (float*)ws;          ws += (size_t)N_TOTAL * 128 * 4;
    float* Hid2 = (float*)ws;          ws += (size_t)N_TOTAL * 128 * 4;
    float* Hid3 = (float*)ws;          ws += (size_t)N_TOTAL * 128 * 4;
    unsigned short* Wth = (unsigned short*)ws;  ws += (size_t)4 * 128 * 128 * 2;
    unsigned short* Wtl = (unsigned short*)ws;  ws += (size_t)4 * 128 * 128 * 2;
    float* tmp  = (float*)ws;          ws += (size_t)N_TOTAL * 4;
    float* lastc= (float*)ws;          ws += (size_t)N_TOTAL * 4;
    int*   topk = (int*)ws;            ws += (size_t)NUM_GRAPHS * KTOP * 4;
    float* y1p  = (float*)ws;          ws += (size_t)NUM_GRAPHS * 16 * 32 * 4;
    unsigned* Au = (unsigned*)ws;      ws += (size_t)NUM_GRAPHS * 512 * 512;       // 16 MB (u8)
    unsigned short* Asw = (unsigned short*)ws;  ws += (size_t)NUM_GRAPHS * 512 * 512 * 2; // 32 MB
    unsigned short* PAh = (unsigned short*)ws;  ws += (size_t)NUM_GRAPHS * 128 * 512 * 2;
    unsigned short* PAl = (unsigned short*)ws;  ws += (size_t)NUM_GRAPHS * 128 * 512 * 2;
    unsigned short* PBh = (unsigned short*)ws;  ws += (size_t)NUM_GRAPHS * 128 * 512 * 2;
    unsigned short* PBl = (unsigned short*)ws;  ws += (size_t)NUM_GRAPHS * 128 * 512 * 2;

    k_init <<<N_TOTAL / 256, 256, 0, stream>>>(deg, cnt);
    k_zero <<<4096, 256, 0, stream>>>((int4*)Au);
    k_build<<<E_TOTAL / 256, 256, 0, stream>>>(ei, deg, cnt, adj, Au);
    k_prep <<<16, 256, 0, stream>>>(Wc, Wth, Wtl);
    k_convA<<<8192, 256, 0, stream>>>(Au, Asw);
    k_embT <<<NUM_GRAPHS * 8, 256, 0, stream>>>(x, emb, PAh, PAl);

    float* Hids[4] = {Hid0, Hid1, Hid2, Hid3};
    unsigned short* Pin_h[4] = {PAh, PBh, PAh, PBh};
    unsigned short* Pin_l[4] = {PAl, PBl, PAl, PBl};
    unsigned short* Pout_h[4] = {PBh, PAh, PBh, nullptr};
    unsigned short* Pout_l[4] = {PBl, PAl, PBl, nullptr};
    for (int l = 0; l < 4; ++l) {
        const float* wl  = (l == 3) ? Wl : nullptr;
        const float* blp = (l == 3) ? bl : nullptr;
        float*       tp  = (l == 3) ? tmp : nullptr;
        k_layer<<<512, 256, 0, stream>>>(Pin_h[l], Pin_l[l], Asw,
                                         Wth + (size_t)l * 16384, Wtl + (size_t)l * 16384,
                                         bc + (size_t)l * 128, wl, blp, tp,
                                         Hids[l], Pout_h[l], Pout_l[l], cnt, deg);
    }
    k_sort <<<NUM_GRAPHS, 256, 0, stream>>>(tmp, adj, cnt, deg, lastc, topk);
    k_conv1<<<NUM_GRAPHS * 4, 256, 0, stream>>>(topk, Hid0, Hid1, Hid2, Hid3, lastc, c1w, c1b, y1p);
    k_tail <<<NUM_GRAPHS, 256, 0, stream>>>(y1p, c2w, c2b, d1w, d1b, d2w, d2b, out);
}

// Round 11
// 326.972 us; speedup vs baseline: 1.6976x; 1.0173x over previous
//
#include <hip/hip_runtime.h>
#include <hip/hip_bf16.h>
#include <math.h>

#define N_TOTAL 32768
#define E_TOTAL 524288
#define NUM_GRAPHS 64
#define NPG 512
#define KTOP 64
#define LATENT 513
#define PPAD 524

typedef __attribute__((ext_vector_type(8))) short bf16x8;
typedef __attribute__((ext_vector_type(4))) float f32x4;

__device__ __forceinline__ unsigned short f2bf(float f) {
    unsigned u = __float_as_uint(f);
    return (unsigned short)((u + 0x7FFFu + ((u >> 16) & 1u)) >> 16);   // RNE
}
__device__ __forceinline__ float bf2f(unsigned short h) {
    return __uint_as_float(((unsigned)h) << 16);
}
// XOR-swizzle within 128B granule keyed by row (write AND read sides)
__device__ __forceinline__ int swz(int bir, int row) {
    return (bir & ~127) | ((bir & 127) ^ ((row & 7) << 4));
}

// ---------------- setup ----------------

__global__ __launch_bounds__(256) void k_init(int* __restrict__ deg, int* __restrict__ cnt) {
    int i = blockIdx.x * 256 + threadIdx.x;
    if (i < N_TOTAL) { deg[i] = 1; cnt[i] = 0; }
}

// deg/cnt only (adj + dense-count scatter eliminated)
__global__ __launch_bounds__(256) void k_build(const int* __restrict__ ei,
                                               int* __restrict__ deg, int* __restrict__ cnt) {
    int e = blockIdx.x * 256 + threadIdx.x;
    if (e >= E_TOTAL) return;
    atomicAdd(&deg[ei[e]], 1);
    atomicAdd(&cnt[ei[E_TOTAL + e]], 1);
}

// Dense bf16 A'[g][v][u] built per (graph, 64-row slice) in LDS — no global atomics.
// Edges of graph g are contiguous: [g*8192, (g+1)*8192).
__global__ __launch_bounds__(256) void k_buildA(const int* __restrict__ ei,
                                                unsigned short* __restrict__ Asw) {
    __shared__ unsigned Acnt[8192];               // 64 rows x 512 byte-counts = 32 KB
    int bid = blockIdx.x;                         // 512 blocks
    int g = bid >> 3, sl = bid & 7;
    int v0 = sl * 64;                             // local row base
    int tid = threadIdx.x;
#pragma unroll
    for (int i = 0; i < 32; ++i) Acnt[tid + i * 256] = 0;
    __syncthreads();
    const int* srcp = ei + (size_t)g * 8192;
    const int* dstp = ei + E_TOTAL + (size_t)g * 8192;
    for (int i = 0; i < 32; ++i) {
        int e = tid + i * 256;
        int d = dstp[e] & 511;                    // local ids (edges stay in-graph)
        int s = srcp[e] & 511;
        if (d >= v0 && d < v0 + 64) {
            int cell = (d - v0) * 512 + s;
            atomicAdd(&Acnt[cell >> 2], 1u << ((cell & 3) << 3));
        }
    }
    __syncthreads();
    // convert (+I on diagonal) -> bf16, coalesced 8B stores
#pragma unroll
    for (int j = 0; j < 32; ++j) {
        int wi = tid + j * 256;                   // word 0..8191 = 4 cells
        unsigned wv = Acnt[wi];
        int cell0 = wi * 4;
        int row = cell0 >> 9, col0 = cell0 & 511;
        int diag = v0 + row;                      // self-loop column (local u == local v)
        unsigned short b[4];
#pragma unroll
        for (int h = 0; h < 4; ++h) {
            float c = (float)((wv >> (8 * h)) & 0xFFu) + ((col0 + h == diag) ? 1.f : 0.f);
            b[h] = f2bf(c);
        }
        *(int2*)(Asw + ((size_t)(g * 512 + v0 + row) << 9) + col0) =
            make_int2((unsigned)b[0] | ((unsigned)b[1] << 16),
                      (unsigned)b[2] | ((unsigned)b[3] << 16));
    }
}

// W prep: transpose + bf16 hi/lo split (proven)
__global__ __launch_bounds__(256) void k_prep(const float* __restrict__ Wc,
                                              unsigned short* __restrict__ Wth,
                                              unsigned short* __restrict__ Wtl) {
    __shared__ float tile[64][65];
    int b = blockIdx.x;
    int l = b >> 2, t = b & 3;
    int k0 = (t >> 1) * 64, o0 = (t & 1) * 64;
    int lane = threadIdx.x & 63, q = threadIdx.x >> 6;
    const float* Wsrc = Wc + (size_t)l * 16384;
#pragma unroll
    for (int it = 0; it < 16; ++it) {
        int r = it * 4 + q;
        tile[r][lane] = Wsrc[(size_t)(k0 + r) * 128 + o0 + lane];
    }
    __syncthreads();
#pragma unroll
    for (int it = 0; it < 16; ++it) {
        int o = it * 4 + q;
        float v = tile[lane][o];
        unsigned short h = f2bf(v);
        unsigned short lo = f2bf(v - bf2f(h));
        size_t dst = (size_t)l * 16384 + (size_t)(o0 + o) * 128 + k0 + lane;
        Wth[dst] = h; Wtl[dst] = lo;
    }
}

// layer-0 panels: emb[x[.]] -> transposed hi/lo panels [g][128ch][512u]  (proven)
__global__ __launch_bounds__(256) void k_embT(const int* __restrict__ x,
                                              const float* __restrict__ emb,
                                              unsigned short* __restrict__ Ph,
                                              unsigned short* __restrict__ Pl) {
    __shared__ float P[64][132];
    __shared__ int nodes[64];
    int b = blockIdx.x;
    int g = b >> 3, ck = b & 7;
    int tid = threadIdx.x;
    if (tid < 64) nodes[tid] = x[g * NPG + ck * 64 + tid];
    __syncthreads();
#pragma unroll
    for (int c = 0; c < 8; ++c) {
        int idx = tid + c * 256;
        int row = idx >> 5, c4 = idx & 31;
        float4 vv = *(const float4*)(emb + (size_t)nodes[row] * 128 + c4 * 4);
        *(float4*)&P[row][c4 * 4] = vv;
    }
    __syncthreads();
#pragma unroll
    for (int c = 0; c < 4; ++c) {
        int idx = tid + c * 256;
        int ch = idx >> 3, grp = idx & 7;
        unsigned hw[4], lw[4];
#pragma unroll
        for (int j = 0; j < 4; ++j) {
            float a  = P[grp * 8 + 2 * j][ch];
            float bq = P[grp * 8 + 2 * j + 1][ch];
            unsigned short ha = f2bf(a),  hb = f2bf(bq);
            unsigned short la = f2bf(a - bf2f(ha)), lb = f2bf(bq - bf2f(hb));
            hw[j] = (unsigned)ha | ((unsigned)hb << 16);
            lw[j] = (unsigned)la | ((unsigned)lb << 16);
        }
        size_t base = ((size_t)g * 128 + ch) * 512 + ck * 64 + grp * 8;
        *(int4*)(Ph + base) = make_int4(hw[0], hw[1], hw[2], hw[3]);
        *(int4*)(Pl + base) = make_int4(lw[0], lw[1], lw[2], lw[3]);
    }
}

// ---------------- fused layer: dense MFMA; B in LDS (async dbuf), A direct-global --------
// (unchanged from round 10 — proven, out of top-5)

__global__ __launch_bounds__(256) void k_layer(const unsigned short* __restrict__ Ph,
                                               const unsigned short* __restrict__ Pl,
                                               const unsigned short* __restrict__ Asw,
                                               const unsigned short* __restrict__ Wth,
                                               const unsigned short* __restrict__ Wtl,
                                               const float* __restrict__ bvec,
                                               const float* __restrict__ Wl,
                                               const float* __restrict__ bl,
                                               float* __restrict__ tmp,
                                               float* __restrict__ Hout,
                                               unsigned short* __restrict__ Poh,
                                               unsigned short* __restrict__ Pol,
                                               const int* __restrict__ cnt,
                                               const int* __restrict__ deg) {
    __shared__ char lds[65536];
    int tid = threadIdx.x;
    int w = tid >> 6, lane = tid & 63;
    int bid = blockIdx.x;
    int g = (bid & 7) * 8 + ((bid >> 3) & 7);
    int vblk = bid >> 6;
    int nodebase = g * NPG + vblk * 64;
    int rowbase = nodebase + w * 16;
    int r = lane & 15, kb = lane >> 4;

    const unsigned short* Pgh = Ph + (size_t)g * 128 * 512;
    const unsigned short* Pgl = Pl + (size_t)g * 128 * 512;
    const unsigned short* Arow = Asw + (size_t)(rowbase + r) * 512;

#define STAGE(buf, kt)                                                                     \
    {                                                                                      \
        _Pragma("unroll")                                                                  \
        for (int c = 0; c < 8; ++c) {                                                      \
            int sb = c * 256 + w * 64;                                                     \
            int slot = sb + lane;                                                          \
            int arr = slot >> 10;                                                          \
            int j = slot & 1023;                                                           \
            int row = j >> 3, off16 = j & 7;                                               \
            const unsigned short* src = (arr ? Pgl : Pgh)                                  \
                + (size_t)row * 512 + (kt) * 64 + ((off16 ^ (row & 7)) << 3);              \
            char* dst = lds + (buf) * 32768 + sb * 16;                                     \
            __builtin_amdgcn_global_load_lds((const unsigned*)src, (unsigned*)dst,         \
                                             16, 0, 0);                                    \
        }                                                                                  \
    }

    f32x4 acc[8];
#pragma unroll
    for (int n = 0; n < 8; ++n) acc[n] = (f32x4){0.f, 0.f, 0.f, 0.f};

    STAGE(0, 0);
    __syncthreads();
    int cbuf = 0;
    for (int kt = 0; kt < 8; ++kt) {
        if (kt < 7) STAGE(cbuf ^ 1, kt + 1);
        const char* cur = lds + cbuf * 32768;
#pragma unroll
        for (int s2 = 0; s2 < 2; ++s2) {
            bf16x8 aA = *(const bf16x8*)(Arow + kt * 64 + s2 * 32 + kb * 8);
#pragma unroll
            for (int n = 0; n < 8; ++n) {
                int ch = n * 16 + r;
                int u = s2 * 4 + kb;
                int boff = ch * 128 + ((u ^ (ch & 7)) << 4);
                bf16x8 bh  = *(const bf16x8*)(cur + boff);
                bf16x8 bl2 = *(const bf16x8*)(cur + 16384 + boff);
                acc[n] = __builtin_amdgcn_mfma_f32_16x16x32_bf16(aA, bh,  acc[n], 0, 0, 0);
                acc[n] = __builtin_amdgcn_mfma_f32_16x16x32_bf16(aA, bl2, acc[n], 0, 0, 0);
            }
        }
        __syncthreads();
        cbuf ^= 1;
    }
#undef STAGE

#pragma unroll
    for (int n = 0; n < 8; ++n) {
#pragma unroll
        for (int q = 0; q < 4; ++q) {
            int v64 = w * 16 + kb * 4 + q;
            int ch = n * 16 + r;
            float s = acc[n][q];
            unsigned short h = f2bf(s), lo = f2bf(s - bf2f(h));
            int addr = v64 * 256 + swz(ch * 2, v64);
            *(unsigned short*)(lds + addr)         = h;
            *(unsigned short*)(lds + 16384 + addr) = lo;
        }
    }
    __syncthreads();

    bf16x8 ah[4], al[4];
#pragma unroll
    for (int ks = 0; ks < 4; ++ks) {
        int v64 = w * 16 + r;
        int addr = v64 * 256 + swz(ks * 64 + kb * 16, v64);
        ah[ks] = *(const bf16x8*)(lds + addr);
        al[ks] = *(const bf16x8*)(lds + 16384 + addr);
    }
    float invd[4], cp1[4];
#pragma unroll
    for (int q = 0; q < 4; ++q) {
        int nd = rowbase + kb * 4 + q;
        invd[q] = 1.0f / (float)deg[nd];
        cp1[q]  = (float)(cnt[nd] + 1);
    }
    float z[4] = {0.f, 0.f, 0.f, 0.f};
    unsigned hiW[8][2], loW[8][2];
#pragma unroll
    for (int ct = 0; ct < 8; ++ct) {
        const unsigned short* Wh = Wth + (size_t)(ct * 16 + r) * 128;
        const unsigned short* Wo = Wtl + (size_t)(ct * 16 + r) * 128;
        f32x4 a = {0.f, 0.f, 0.f, 0.f};
#pragma unroll
        for (int ks = 0; ks < 4; ++ks) {
            bf16x8 wh = *(const bf16x8*)(Wh + ks * 32 + kb * 8);
            bf16x8 wl = *(const bf16x8*)(Wo + ks * 32 + kb * 8);
            a = __builtin_amdgcn_mfma_f32_16x16x32_bf16(ah[ks], wh, a, 0, 0, 0);
            a = __builtin_amdgcn_mfma_f32_16x16x32_bf16(ah[ks], wl, a, 0, 0, 0);
            a = __builtin_amdgcn_mfma_f32_16x16x32_bf16(al[ks], wh, a, 0, 0, 0);
        }
        float bcol = bvec[ct * 16 + r];
        float wlast = Wl ? Wl[ct * 16 + r] : 0.f;
        unsigned short hq[4], lq[4];
#pragma unroll
        for (int q = 0; q < 4; ++q) {
            float val = tanhf((a[q] + bcol * cp1[q]) * invd[q]);
            Hout[(size_t)(rowbase + kb * 4 + q) * 128 + ct * 16 + r] = val;
            z[q] = fmaf(val, wlast, z[q]);
            hq[q] = f2bf(val);
            lq[q] = f2bf(val - bf2f(hq[q]));
        }
        hiW[ct][0] = (unsigned)hq[0] | ((unsigned)hq[1] << 16);
        hiW[ct][1] = (unsigned)hq[2] | ((unsigned)hq[3] << 16);
        loW[ct][0] = (unsigned)lq[0] | ((unsigned)lq[1] << 16);
        loW[ct][1] = (unsigned)lq[2] | ((unsigned)lq[3] << 16);
    }

    if (Poh) {
        __syncthreads();
#pragma unroll
        for (int ct = 0; ct < 8; ++ct) {
            int o = ct * 16 + r;
            int v64 = w * 16 + kb * 4;
            int addr = o * 128 + swz(v64 * 2, o);
            *(int2*)(lds + addr)         = make_int2(hiW[ct][0], hiW[ct][1]);
            *(int2*)(lds + 16384 + addr) = make_int2(loW[ct][0], loW[ct][1]);
        }
        __syncthreads();
#pragma unroll
        for (int c = 0; c < 8; ++c) {
            int idx = tid + c * 256;
            int arr = idx >> 10;
            int j = idx & 1023;
            int o = j >> 3, off16 = j & 7;
            int4 v = *(const int4*)(lds + arr * 16384 + o * 128 + swz(off16 * 16, o));
            unsigned short* dst = (arr ? Pol : Poh) + ((size_t)g * 128 + o) * 512 + vblk * 64 + off16 * 8;
            *(int4*)dst = v;
        }
    }

    if (Wl) {
#pragma unroll
        for (int m = 1; m < 16; m <<= 1) {
            z[0] += __shfl_xor(z[0], m); z[1] += __shfl_xor(z[1], m);
            z[2] += __shfl_xor(z[2], m); z[3] += __shfl_xor(z[3], m);
        }
        if (r == 0) {
            float b0 = bl[0];
#pragma unroll
            for (int q = 0; q < 4; ++q) tmp[rowbase + kb * 4 + q] = z[q] + b0;
        }
    }
}

// ---------------- last-channel aggregation via dense A' (replaces adj gather) ----------

__global__ __launch_bounds__(256) void k_lastagg(const unsigned short* __restrict__ Asw,
                                                 const float* __restrict__ tmp,
                                                 const int* __restrict__ deg,
                                                 float* __restrict__ lastc) {
    __shared__ float t[512];
    int bid = blockIdx.x;                 // 512 blocks: graph x 64-row slice
    int g = bid >> 3, sl = bid & 7;
    int tid = threadIdx.x;
    if (tid < 128) *(float4*)&t[tid * 4] = *(const float4*)(tmp + (size_t)g * 512 + tid * 4);
    __syncthreads();
    int row = tid >> 2, q = tid & 3;      // 4 threads per row, 128-col quarter each
    int v = g * NPG + sl * 64 + row;
    const unsigned short* Ar = Asw + ((size_t)v << 9) + q * 128;
    float s = 0.f;
#pragma unroll
    for (int c = 0; c < 128; c += 8) {
        bf16x8 a8 = *(const bf16x8*)(Ar + c);
#pragma unroll
        for (int h = 0; h < 8; ++h)
            s = fmaf(bf2f((unsigned short)a8[h]), t[q * 128 + c + h], s);
    }
    s += __shfl_xor(s, 1);
    s += __shfl_xor(s, 2);
    if (q == 0) lastc[v] = tanhf(s / (float)deg[v]);
}

// ---------------- sort pool: pure bitonic (val desc, idx asc) ----------------

__global__ __launch_bounds__(256) void k_sort(const float* __restrict__ lastc,
                                              int* __restrict__ topk) {
    __shared__ float v[512];
    __shared__ int ix[512];
    int g = blockIdx.x, tid = threadIdx.x;
    for (int i = tid; i < 512; i += 256) { v[i] = lastc[g * NPG + i]; ix[i] = i; }
    __syncthreads();
    for (int ksz = 2; ksz <= 512; ksz <<= 1) {
        for (int jj = ksz >> 1; jj > 0; jj >>= 1) {
            for (int i = tid; i < 512; i += 256) {
                int p = i ^ jj;
                if (p > i) {
                    float va = v[i], vb = v[p];
                    int ia = ix[i], ib = ix[p];
                    bool b_before_a = (vb > va) || (vb == va && ib < ia);
                    bool up = (i & ksz) == 0;
                    bool sw = up ? b_before_a : !b_before_a;
                    if (sw) { v[i] = vb; v[p] = va; ix[i] = ib; ix[p] = ia; }
                }
            }
            __syncthreads();
        }
    }
    for (int k = tid; k < KTOP; k += 256) topk[g * KTOP + k] = g * NPG + ix[k];
}

// ---------------- conv1 + relu + maxpool ----------------

__global__ __launch_bounds__(256) void k_conv1(const int* __restrict__ topk,
                                               const float* __restrict__ h0,
                                               const float* __restrict__ h1,
                                               const float* __restrict__ h2,
                                               const float* __restrict__ h3,
                                               const float* __restrict__ lastc,
                                               const float* __restrict__ c1w,
                                               const float* __restrict__ c1b,
                                               float* __restrict__ y1p) {
    __shared__ float P[16][PPAD];
    __shared__ float Y1c[16][16];
    __shared__ int nodes[16];
    int bid = blockIdx.x;
    int g = bid >> 2, cc = bid & 3;
    int tid = threadIdx.x;
    if (tid < 16) nodes[tid] = topk[g * KTOP + cc * 16 + tid];
    __syncthreads();
    {
        int r = tid >> 4, t4 = tid & 15;
        int node = nodes[r];
#pragma unroll
        for (int jj = 0; jj < 8; ++jj) {
            int d = (t4 + 16 * jj) * 4;
            const float* src = (d < 128) ? h0 : (d < 256) ? h1 : (d < 384) ? h2 : h3;
            float4 val = *(const float4*)(src + (size_t)node * 128 + (d & 127));
            *(float4*)&P[r][d] = val;
        }
        if (t4 == 0) P[r][512] = lastc[node];
    }
    __syncthreads();
    int o = tid >> 4, kk = tid & 15;
    const float* w = c1w + (size_t)o * LATENT;
    float a0 = 0.f, a1 = 0.f, a2 = 0.f, a3 = 0.f;
    for (int d = 0; d < 512; d += 4) {
        float4 p = *(const float4*)&P[kk][d];
        a0 = fmaf(p.x, w[d],     a0);
        a1 = fmaf(p.y, w[d + 1], a1);
        a2 = fmaf(p.z, w[d + 2], a2);
        a3 = fmaf(p.w, w[d + 3], a3);
    }
    float s = ((a0 + a1) + (a2 + a3)) + P[kk][512] * w[512] + c1b[o];
    Y1c[o][kk] = fmaxf(s, 0.f);
    __syncthreads();
    if (tid < 128) {
        int oo = tid >> 3, l = tid & 7;
        y1p[(size_t)g * 512 + oo * 32 + cc * 8 + l] = fmaxf(Y1c[oo][2 * l], Y1c[oo][2 * l + 1]);
    }
}

// ---------------- conv2 + dense + softmax ----------------

__global__ __launch_bounds__(256) void k_tail(const float* __restrict__ y1p,
                                              const float* __restrict__ c2w, const float* __restrict__ c2b,
                                              const float* __restrict__ d1w, const float* __restrict__ d1b,
                                              const float* __restrict__ d2w, const float* __restrict__ d2b,
                                              float* __restrict__ out) {
    __shared__ float Y1P[16][32];
    __shared__ float Y2[32][28];
    __shared__ float H1s[32];
    __shared__ float red[256];
    int g = blockIdx.x, tid = threadIdx.x;
    for (int t = tid; t < 512; t += 256) ((float*)Y1P)[t] = y1p[(size_t)g * 512 + t];
    __syncthreads();
    for (int t = tid; t < 32 * 28; t += 256) {
        int o2 = t / 28, tt = t - o2 * 28;
        float s = c2b[o2];
#pragma unroll
        for (int i = 0; i < 16; ++i)
#pragma unroll
            for (int dt = 0; dt < 5; ++dt)
                s = fmaf(Y1P[i][tt + dt], c2w[o2 * 80 + i * 5 + dt], s);
        Y2[o2][tt] = fmaxf(s, 0.f);
    }
    __syncthreads();
    {
        int jcol = tid >> 3, part = tid & 7;
        float s = 0.f;
        for (int rr = 0; rr < 4; ++rr) {
            int o2 = part * 4 + rr;
            int base = o2 * 28;
            for (int tt = 0; tt < 28; ++tt)
                s = fmaf(Y2[o2][tt], d1w[(size_t)(base + tt) * 32 + jcol], s);
        }
        red[tid] = s;
        __syncthreads();
        if (part == 0) {
            float t = 0.f;
#pragma unroll
            for (int p = 0; p < 8; ++p) t += red[tid + p];
            H1s[jcol] = fmaxf(t + d1b[jcol], 0.f);
        }
        __syncthreads();
    }
    if (tid == 0) {
        float l0 = d2b[0], l1 = d2b[1];
        for (int jc = 0; jc < 32; ++jc) {
            l0 = fmaf(H1s[jc], d2w[jc * 2 + 0], l0);
            l1 = fmaf(H1s[jc], d2w[jc * 2 + 1], l1);
        }
        float m = fmaxf(l0, l1);
        float e0 = expf(l0 - m), e1 = expf(l1 - m);
        float inv = 1.f / (e0 + e1);
        out[g * 2 + 0] = e0 * inv;
        out[g * 2 + 1] = e1 * inv;
    }
}

// ---------------- launch ----------------

extern "C" void kernel_launch(void* const* d_in, const int* in_sizes, int n_in,
                              void* d_out, int out_size, void* d_ws, size_t ws_size,
                              hipStream_t stream) {
    const int*   x    = (const int*)d_in[0];
    const int*   ei   = (const int*)d_in[1];
    const float* emb  = (const float*)d_in[3];
    const float* Wc   = (const float*)d_in[4];
    const float* bc   = (const float*)d_in[5];
    const float* Wl   = (const float*)d_in[6];
    const float* bl   = (const float*)d_in[7];
    const float* c1w  = (const float*)d_in[8];
    const float* c1b  = (const float*)d_in[9];
    const float* c2w  = (const float*)d_in[10];
    const float* c2b  = (const float*)d_in[11];
    const float* d1w  = (const float*)d_in[12];
    const float* d1b  = (const float*)d_in[13];
    const float* d2w  = (const float*)d_in[14];
    const float* d2b  = (const float*)d_in[15];
    float* out = (float*)d_out;

    char* ws = (char*)d_ws;
    int*   deg  = (int*)ws;            ws += (size_t)N_TOTAL * 4;
    int*   cnt  = (int*)ws;            ws += (size_t)N_TOTAL * 4;
    float* Hid0 = (float*)ws;          ws += (size_t)N_TOTAL * 128 * 4;
    float* Hid1 = (float*)ws;          ws += (size_t)N_TOTAL * 128 * 4;
    float* Hid2 = (float*)ws;          ws += (size_t)N_TOTAL * 128 * 4;
    float* Hid3 = (float*)ws;          ws += (size_t)N_TOTAL * 128 * 4;
    unsigned short* Wth = (unsigned short*)ws;  ws += (size_t)4 * 128 * 128 * 2;
    unsigned short* Wtl = (unsigned short*)ws;  ws += (size_t)4 * 128 * 128 * 2;
    float* tmp  = (float*)ws;          ws += (size_t)N_TOTAL * 4;
    float* lastc= (float*)ws;          ws += (size_t)N_TOTAL * 4;
    int*   topk = (int*)ws;            ws += (size_t)NUM_GRAPHS * KTOP * 4;
    float* y1p  = (float*)ws;          ws += (size_t)NUM_GRAPHS * 16 * 32 * 4;
    unsigned short* Asw = (unsigned short*)ws;  ws += (size_t)NUM_GRAPHS * 512 * 512 * 2; // 32 MB
    unsigned short* PAh = (unsigned short*)ws;  ws += (size_t)NUM_GRAPHS * 128 * 512 * 2;
    unsigned short* PAl = (unsigned short*)ws;  ws += (size_t)NUM_GRAPHS * 128 * 512 * 2;
    unsigned short* PBh = (unsigned short*)ws;  ws += (size_t)NUM_GRAPHS * 128 * 512 * 2;
    unsigned short* PBl = (unsigned short*)ws;  ws += (size_t)NUM_GRAPHS * 128 * 512 * 2;

    k_init  <<<N_TOTAL / 256, 256, 0, stream>>>(deg, cnt);
    k_build <<<E_TOTAL / 256, 256, 0, stream>>>(ei, deg, cnt);
    k_prep  <<<16, 256, 0, stream>>>(Wc, Wth, Wtl);
    k_buildA<<<512, 256, 0, stream>>>(ei, Asw);
    k_embT  <<<NUM_GRAPHS * 8, 256, 0, stream>>>(x, emb, PAh, PAl);

    float* Hids[4] = {Hid0, Hid1, Hid2, Hid3};
    unsigned short* Pin_h[4] = {PAh, PBh, PAh, PBh};
    unsigned short* Pin_l[4] = {PAl, PBl, PAl, PBl};
    unsigned short* Pout_h[4] = {PBh, PAh, PBh, nullptr};
    unsigned short* Pout_l[4] = {PBl, PAl, PBl, nullptr};
    for (int l = 0; l < 4; ++l) {
        const float* wl  = (l == 3) ? Wl : nullptr;
        const float* blp = (l == 3) ? bl : nullptr;
        float*       tp  = (l == 3) ? tmp : nullptr;
        k_layer<<<512, 256, 0, stream>>>(Pin_h[l], Pin_l[l], Asw,
                                         Wth + (size_t)l * 16384, Wtl + (size_t)l * 16384,
                                         bc + (size_t)l * 128, wl, blp, tp,
                                         Hids[l], Pout_h[l], Pout_l[l], cnt, deg);
    }
    k_lastagg<<<512, 256, 0, stream>>>(Asw, tmp, deg, lastc);
    k_sort   <<<NUM_GRAPHS, 256, 0, stream>>>(lastc, topk);
    k_conv1  <<<NUM_GRAPHS * 4, 256, 0, stream>>>(topk, Hid0, Hid1, Hid2, Hid3, lastc, c1w, c1b, y1p);
    k_tail   <<<NUM_GRAPHS, 256, 0, stream>>>(y1p, c2w, c2b, d1w, d1b, d2w, d2b, out);
}